// Round 1
// baseline (1213.109 us; speedup 1.0000x reference)
//
#include <hip/hip_runtime.h>

// LSTM scan: T=2048 steps, B=4096 rows, IN=8, HID=20 (4H=80 gate cols).
// Mapping: 16 threads per batch row (5 gate-cols each), 4 rows/wave (64 lanes
// exact), block=256 -> 16 rows, grid=256 -> 1 block/CU, 1 wave/SIMD.
// All cross-thread exchange (h broadcast, gate gather) is intra-wave via LDS:
// per-wave DS pipe is in-order, so no __syncthreads anywhere; wave_barrier()
// fences stop compiler reordering of the may-alias LDS ops.

typedef float f32x2 __attribute__((ext_vector_type(2)));
typedef float f32x4 __attribute__((ext_vector_type(4)));

#define TSTEPS 2048
#define NBATCH 4096
#define LOG2E  1.4426950408889634f

__device__ __forceinline__ float ex2_(float v) {
#if __has_builtin(__builtin_amdgcn_exp2f)
    return __builtin_amdgcn_exp2f(v);   // v_exp_f32: D = 2^S0
#else
    return exp2f(v);
#endif
}
__device__ __forceinline__ float rcp_(float v) {
#if __has_builtin(__builtin_amdgcn_rcpf)
    return __builtin_amdgcn_rcpf(v);    // v_rcp_f32, ~1 ulp
#else
    return 1.0f / v;
#endif
}
__device__ __forceinline__ f32x2 lo2(f32x4 v) { return __builtin_shufflevector(v, v, 0, 1); }
__device__ __forceinline__ f32x2 hi2(f32x4 v) { return __builtin_shufflevector(v, v, 2, 3); }
__device__ __forceinline__ f32x2 pkfma(f32x2 a, f32x2 b, f32x2 c) {
#if __has_builtin(__builtin_elementwise_fma)
    return __builtin_elementwise_fma(a, b, c);  // -> v_pk_fma_f32 (2x fp32 rate)
#else
    return a * b + c;
#endif
}
__device__ __forceinline__ void fence_() {
#if __has_builtin(__builtin_amdgcn_wave_barrier)
    __builtin_amdgcn_wave_barrier();
#else
    __syncthreads();
#endif
}

__global__ __launch_bounds__(256, 1)
void lstm_scan(const float* __restrict__ x,
               const float* __restrict__ W_ih,
               const float* __restrict__ b_ih,
               const float* __restrict__ W_hh,
               const float* __restrict__ b_hh,
               const float* __restrict__ hx0,
               const float* __restrict__ cx0,
               float* __restrict__ out)
{
    const int lane = threadIdx.x & 63;
    const int wv   = threadIdx.x >> 6;
    const int blw  = lane >> 4;           // batch row within wave (0..3)
    const int q    = lane & 15;           // column group (0..15), 5 cols each
    const int bl   = wv * 4 + blw;        // batch row within block (0..15)
    const int b    = blockIdx.x * 16 + bl;

    // h state: [row][unit], 80B rows -> f32x4-aligned, broadcast reads.
    __shared__ __align__(16) float h_lds[16][20];
    // activated gates: [type 0..3][row][unit]
    __shared__ float g_lds[4 * 16 * 20];

    const int c0 = 5 * q;   // my 5 gate columns: c0..c0+4 (all same gate type)

    // ---- loop-invariant weights in registers, packed over k for v_pk_fma ----
    f32x2 wih2[4][5];
    #pragma unroll
    for (int i2 = 0; i2 < 4; ++i2)
        #pragma unroll
        for (int m = 0; m < 5; ++m) {
            f32x2 w;
            w.x = W_ih[(2 * i2) * 80 + c0 + m];
            w.y = W_ih[(2 * i2 + 1) * 80 + c0 + m];
            wih2[i2][m] = w;
        }
    f32x2 whh2[10][5];
    #pragma unroll
    for (int k2 = 0; k2 < 10; ++k2)
        #pragma unroll
        for (int m = 0; m < 5; ++m) {
            f32x2 w;
            w.x = W_hh[(2 * k2) * 80 + c0 + m];
            w.y = W_hh[(2 * k2 + 1) * 80 + c0 + m];
            whh2[k2][m] = w;
        }
    f32x2 bias2[5];
    #pragma unroll
    for (int m = 0; m < 5; ++m) {
        f32x2 t; t.x = b_ih[c0 + m] + b_hh[c0 + m]; t.y = 0.0f;
        bias2[m] = t;
    }

    // activation = fma(as, rcp(1 + exp2(amul*v)), at): sigmoid or tanh, branchless
    const bool isg  = ((q >> 2) == 2);            // cols 40..59 = g block -> tanh
    const float amul = isg ? (2.0f * LOG2E) : (-LOG2E);
    const float as_  = isg ? -2.0f : 1.0f;
    const float at_  = isg ?  1.0f : 0.0f;

    // ---- init state ----
    float c1 = cx0[q];
    float c2 = (q < 4) ? cx0[16 + q] : 0.0f;
    float hy1 = 0.0f, hy2 = 0.0f;
    h_lds[bl][q] = hx0[q];
    if (q < 4) h_lds[bl][16 + q] = hx0[16 + q];
    fence_();

    // ---- x prefetch: two register buffers, distance-2 pipeline ----
    const f32x4* xp = (const f32x4*)(x + (size_t)b * 8);  // stride 8192 f32x4/step
    f32x4 x00 = xp[0], x01 = xp[1];                        // x_0
    f32x4 xB0 = xp[(size_t)1 * 8192], xB1 = xp[(size_t)1 * 8192 + 1];  // x_1
    f32x4 xA0 = xp[(size_t)2 * 8192], xA1 = xp[(size_t)2 * 8192 + 1];  // x_2

    // acc2 entering iter t holds bias + x_t · W_ih (packed partial sums)
    f32x2 acc2[5];
    #pragma unroll
    for (int m = 0; m < 5; ++m) acc2[m] = bias2[m];
    #pragma unroll
    for (int m = 0; m < 5; ++m) {
        acc2[m] = pkfma(lo2(x00), wih2[0][m], acc2[m]);
        acc2[m] = pkfma(hi2(x00), wih2[1][m], acc2[m]);
        acc2[m] = pkfma(lo2(x01), wih2[2][m], acc2[m]);
        acc2[m] = pkfma(hi2(x01), wih2[3][m], acc2[m]);
    }

    auto body = [&](int t, f32x4& bx0, f32x4& bx1) {
        // (1) broadcast-read h_{t-1} (written by owners last iter, same wave)
        const f32x4* hv = (const f32x4*)(&h_lds[bl][0]);
        f32x4 ha = hv[0], hb = hv[1], hc = hv[2], hd = hv[3], he = hv[4];
        f32x2 hp[10] = { lo2(ha), hi2(ha), lo2(hb), hi2(hb), lo2(hc),
                         hi2(hc), lo2(hd), hi2(hd), lo2(he), hi2(he) };
        // (2) gates += h · W_hh  (50 v_pk_fma_f32)
        #pragma unroll
        for (int k2 = 0; k2 < 10; ++k2)
            #pragma unroll
            for (int m = 0; m < 5; ++m)
                acc2[m] = pkfma(hp[k2], whh2[k2][m], acc2[m]);
        // (3,4) reduce pairs + activate (branchless sigmoid/tanh)
        float av[5];
        #pragma unroll
        for (int m = 0; m < 5; ++m) {
            float v = acc2[m].x + acc2[m].y;
            float r = rcp_(1.0f + ex2_(amul * v));
            av[m] = fmaf(as_, r, at_);
        }
        // (5) publish activated gates
        const int wb = (q >> 2) * 320 + bl * 20 + 5 * (q & 3);
        #pragma unroll
        for (int m = 0; m < 5; ++m) g_lds[wb + m] = av[m];
        // (6) overlap gate round-trip: next step's x partials + x prefetch
        #pragma unroll
        for (int m = 0; m < 5; ++m) acc2[m] = bias2[m];
        #pragma unroll
        for (int m = 0; m < 5; ++m) {
            acc2[m] = pkfma(lo2(bx0), wih2[0][m], acc2[m]);
            acc2[m] = pkfma(hi2(bx0), wih2[1][m], acc2[m]);
            acc2[m] = pkfma(lo2(bx1), wih2[2][m], acc2[m]);
            acc2[m] = pkfma(hi2(bx1), wih2[3][m], acc2[m]);
        }
        int tl = t + 3; if (tl > TSTEPS - 1) tl = TSTEPS - 1;   // tail clamp
        bx0 = xp[(size_t)tl * 8192];
        bx1 = xp[(size_t)tl * 8192 + 1];
        fence_();
        // (7,8) cell update for owned unit(s): j = q, and j = 16+q for q<4
        const int gb = bl * 20 + q;
        float iv = g_lds[gb], fv = g_lds[320 + gb], gv = g_lds[640 + gb], ov = g_lds[960 + gb];
        c1 = fmaf(fv, c1, iv * gv);
        float th1 = fmaf(-2.0f, rcp_(1.0f + ex2_(2.0f * LOG2E * c1)), 1.0f);
        hy1 = ov * th1;
        h_lds[bl][q] = hy1;
        if (q < 4) {
            const int gb2 = bl * 20 + 16 + q;
            float iv2 = g_lds[gb2], fv2 = g_lds[320 + gb2],
                  gv2 = g_lds[640 + gb2], ov2 = g_lds[960 + gb2];
            c2 = fmaf(fv2, c2, iv2 * gv2);
            float th2 = fmaf(-2.0f, rcp_(1.0f + ex2_(2.0f * LOG2E * c2)), 1.0f);
            hy2 = ov2 * th2;
            h_lds[bl][16 + q] = hy2;
        }
        fence_();
    };

    for (int t = 0; t < TSTEPS; t += 2) {   // 2x unroll keeps buffers static
        body(t,     xB0, xB1);
        body(t + 1, xA0, xA1);
    }

    out[b * 20 + q] = hy1;
    if (q < 4) out[b * 20 + 16 + q] = hy2;
}

extern "C" void kernel_launch(void* const* d_in, const int* in_sizes, int n_in,
                              void* d_out, int out_size, void* d_ws, size_t ws_size,
                              hipStream_t stream) {
    const float* x    = (const float*)d_in[0];
    const float* W_ih = (const float*)d_in[1];
    const float* b_ih = (const float*)d_in[2];
    const float* W_hh = (const float*)d_in[3];
    const float* b_hh = (const float*)d_in[4];
    const float* hx0  = (const float*)d_in[5];
    const float* cx0  = (const float*)d_in[6];
    float* out = (float*)d_out;

    lstm_scan<<<dim3(256), dim3(256), 0, stream>>>(x, W_ih, b_ih, W_hh, b_hh,
                                                   hx0, cx0, out);
}

// Round 4
// 1088.276 us; speedup vs baseline: 1.1147x; 1.1147x over previous
//
#include <hip/hip_runtime.h>

// LSTM scan: T=2048, B=4096, IN=8, HID=20 (80 gate cols).
// 16 lanes/row (5 gate cols each), 4 rows/wave, block=256 (16 rows),
// grid=256 -> 1 block/CU, 1 wave/SIMD (hard ceiling: 4096*16 = 1024 waves).
// R2: forced v_pk_fma_f32/pk_mul/pk_add via inline asm (R1 showed the
// compiler scalarized float2 fma: VALUBusy 2.3x the packed estimate);
// g_lds re-laid out as [row][unit][gate] -> conflict-free scattered b32
// writes (32 distinct banks) + single ds_read_b128 per cell update
// (R1 layout had 4-way write conflicts: 8.4e7 conflict cycles).
// [R2 resubmit x2: rounds 2-3 benches were GPUAcquisitionTimeouts]

typedef float f32x2 __attribute__((ext_vector_type(2)));
typedef float f32x4 __attribute__((ext_vector_type(4)));

#define TSTEPS 2048
#define LOG2E  1.4426950408889634f

__device__ __forceinline__ float ex2_(float v) {
#if __has_builtin(__builtin_amdgcn_exp2f)
    return __builtin_amdgcn_exp2f(v);
#else
    return exp2f(v);
#endif
}
__device__ __forceinline__ float rcp_(float v) {
#if __has_builtin(__builtin_amdgcn_rcpf)
    return __builtin_amdgcn_rcpf(v);
#else
    return 1.0f / v;
#endif
}
__device__ __forceinline__ f32x2 lo2(f32x4 v) { return __builtin_shufflevector(v, v, 0, 1); }
__device__ __forceinline__ f32x2 hi2(f32x4 v) { return __builtin_shufflevector(v, v, 2, 3); }

// Forced packed fp32 math (VOP3P). R1 evidence: compiler scalarized
// __builtin_elementwise_fma on float2 (VALUBusy matched 2x inst count).
__device__ __forceinline__ f32x2 pkfma(f32x2 a, f32x2 b, f32x2 c) {
    f32x2 d;
    asm("v_pk_fma_f32 %0, %1, %2, %3" : "=v"(d) : "v"(a), "v"(b), "v"(c));
    return d;
}
__device__ __forceinline__ f32x2 pkmul(f32x2 a, f32x2 b) {
    f32x2 d;
    asm("v_pk_mul_f32 %0, %1, %2" : "=v"(d) : "v"(a), "v"(b));
    return d;
}
__device__ __forceinline__ f32x2 pkadd(f32x2 a, f32x2 b) {
    f32x2 d;
    asm("v_pk_add_f32 %0, %1, %2" : "=v"(d) : "v"(a), "v"(b));
    return d;
}
__device__ __forceinline__ void fence_() {
#if __has_builtin(__builtin_amdgcn_wave_barrier)
    __builtin_amdgcn_wave_barrier();
#else
    __syncthreads();
#endif
}

__global__ __launch_bounds__(256, 1)
void lstm_scan(const float* __restrict__ x,
               const float* __restrict__ W_ih,
               const float* __restrict__ b_ih,
               const float* __restrict__ W_hh,
               const float* __restrict__ b_hh,
               const float* __restrict__ hx0,
               const float* __restrict__ cx0,
               float* __restrict__ out)
{
    const int lane = threadIdx.x & 63;
    const int wv   = threadIdx.x >> 6;
    const int blw  = lane >> 4;           // batch row within wave (0..3)
    const int q    = lane & 15;           // column group (0..15)
    const int bl   = wv * 4 + blw;        // batch row within block (0..15)
    const int b    = blockIdx.x * 16 + bl;

    // h state: [row][unit], 80B rows (f32x4-aligned broadcast reads, banks
    // bl*20%32 = {0,20,8,28} -> the 4 distinct b128 spans are conflict-free).
    __shared__ __align__(16) float h_lds[16][20];
    // activated gates: [row][unit][gate] -- unit stride 4 floats.
    // Writes: bank = (80bl + 20qq + 4m + ty) % 32 -> all 64 lanes distinct.
    // Cell read: one aligned ds_read_b128 per unit (i,f,g,o contiguous).
    __shared__ __align__(16) float g_lds[16 * 80];

    const int c0 = 5 * q;                 // my 5 gate cols (same gate type)
    const int ty = q >> 2;                // gate type 0..3 (i,f,g,o)
    const int qq = q & 3;                 // unit-block within type

    // ---- loop-invariant weights, packed over k ----
    f32x2 wih2[4][5];
    #pragma unroll
    for (int i2 = 0; i2 < 4; ++i2)
        #pragma unroll
        for (int m = 0; m < 5; ++m) {
            f32x2 w;
            w.x = W_ih[(2 * i2) * 80 + c0 + m];
            w.y = W_ih[(2 * i2 + 1) * 80 + c0 + m];
            wih2[i2][m] = w;
        }
    f32x2 whh2[10][5];
    #pragma unroll
    for (int k2 = 0; k2 < 10; ++k2)
        #pragma unroll
        for (int m = 0; m < 5; ++m) {
            f32x2 w;
            w.x = W_hh[(2 * k2) * 80 + c0 + m];
            w.y = W_hh[(2 * k2 + 1) * 80 + c0 + m];
            whh2[k2][m] = w;
        }
    f32x2 bias2[5];
    #pragma unroll
    for (int m = 0; m < 5; ++m) {
        f32x2 t; t.x = b_ih[c0 + m] + b_hh[c0 + m]; t.y = 0.0f;
        bias2[m] = t;
    }

    // branchless activation: fma(as, rcp(1 + exp2(amul*v)), at)
    const bool isg   = (ty == 2);
    const float amul = isg ? (2.0f * LOG2E) : (-LOG2E);
    const float as_  = isg ? -2.0f : 1.0f;
    const float at_  = isg ?  1.0f : 0.0f;
    f32x2 AM2; AM2.x = amul; AM2.y = amul;
    f32x2 AS2; AS2.x = as_;  AS2.y = as_;
    f32x2 AT2; AT2.x = at_;  AT2.y = at_;
    f32x2 ONE2; ONE2.x = 1.0f; ONE2.y = 1.0f;

    // ---- init state ----
    float c1 = cx0[q];
    float c2 = (q < 4) ? cx0[16 + q] : 0.0f;
    float hy1 = 0.0f, hy2 = 0.0f;
    h_lds[bl][q] = hx0[q];
    if (q < 4) h_lds[bl][16 + q] = hx0[16 + q];
    fence_();

    // ---- x prefetch pipeline (distance 2) ----
    const f32x4* xp = (const f32x4*)(x + (size_t)b * 8);
    f32x4 x00 = xp[0], x01 = xp[1];
    f32x4 xB0 = xp[(size_t)1 * 8192], xB1 = xp[(size_t)1 * 8192 + 1];
    f32x4 xA0 = xp[(size_t)2 * 8192], xA1 = xp[(size_t)2 * 8192 + 1];

    f32x2 acc2[5];
    #pragma unroll
    for (int m = 0; m < 5; ++m) acc2[m] = bias2[m];
    #pragma unroll
    for (int m = 0; m < 5; ++m) {
        acc2[m] = pkfma(lo2(x00), wih2[0][m], acc2[m]);
        acc2[m] = pkfma(hi2(x00), wih2[1][m], acc2[m]);
        acc2[m] = pkfma(lo2(x01), wih2[2][m], acc2[m]);
        acc2[m] = pkfma(hi2(x01), wih2[3][m], acc2[m]);
    }

    const int gwb = bl * 80 + 20 * qq + ty;  // write base: + 4m per col
    const int grb = bl * 80 + 4 * q;         // cell read base (b128)

    auto body = [&](int t, f32x4& bx0, f32x4& bx1) {
        // (1) broadcast-read h_{t-1}
        const f32x4* hv = (const f32x4*)(&h_lds[bl][0]);
        f32x4 ha = hv[0], hb = hv[1], hc = hv[2], hd = hv[3], he = hv[4];
        f32x2 hp[10] = { lo2(ha), hi2(ha), lo2(hb), hi2(hb), lo2(hc),
                         hi2(hc), lo2(hd), hi2(hd), lo2(he), hi2(he) };
        // (2) gates += h . W_hh  (50 forced v_pk_fma_f32)
        #pragma unroll
        for (int k2 = 0; k2 < 10; ++k2)
            #pragma unroll
            for (int m = 0; m < 5; ++m)
                acc2[m] = pkfma(hp[k2], whh2[k2][m], acc2[m]);
        // (3) horizontal reduce + packed activation
        float v0 = acc2[0].x + acc2[0].y, v1 = acc2[1].x + acc2[1].y;
        float v2 = acc2[2].x + acc2[2].y, v3 = acc2[3].x + acc2[3].y;
        float v4 = acc2[4].x + acc2[4].y;
        f32x2 V01; V01.x = v0; V01.y = v1;
        f32x2 V23; V23.x = v2; V23.y = v3;
        f32x2 Z01 = pkmul(AM2, V01), Z23 = pkmul(AM2, V23);
        float z4 = amul * v4;
        f32x2 E01; E01.x = ex2_(Z01.x); E01.y = ex2_(Z01.y);
        f32x2 E23; E23.x = ex2_(Z23.x); E23.y = ex2_(Z23.y);
        float e4 = ex2_(z4);
        f32x2 P01 = pkadd(ONE2, E01), P23 = pkadd(ONE2, E23);
        float p4 = 1.0f + e4;
        f32x2 R01; R01.x = rcp_(P01.x); R01.y = rcp_(P01.y);
        f32x2 R23; R23.x = rcp_(P23.x); R23.y = rcp_(P23.y);
        float r4 = rcp_(p4);
        f32x2 A01 = pkfma(AS2, R01, AT2), A23 = pkfma(AS2, R23, AT2);
        float a4 = fmaf(as_, r4, at_);
        // (5) publish gates: scattered b32, conflict-free banks
        g_lds[gwb +  0] = A01.x;
        g_lds[gwb +  4] = A01.y;
        g_lds[gwb +  8] = A23.x;
        g_lds[gwb + 12] = A23.y;
        g_lds[gwb + 16] = a4;
        // (6) overlap gate round-trip: next step's x partials + prefetch
        #pragma unroll
        for (int m = 0; m < 5; ++m) acc2[m] = bias2[m];
        #pragma unroll
        for (int m = 0; m < 5; ++m) {
            acc2[m] = pkfma(lo2(bx0), wih2[0][m], acc2[m]);
            acc2[m] = pkfma(hi2(bx0), wih2[1][m], acc2[m]);
            acc2[m] = pkfma(lo2(bx1), wih2[2][m], acc2[m]);
            acc2[m] = pkfma(hi2(bx1), wih2[3][m], acc2[m]);
        }
        int tl = t + 3; if (tl > TSTEPS - 1) tl = TSTEPS - 1;
        bx0 = xp[(size_t)tl * 8192];
        bx1 = xp[(size_t)tl * 8192 + 1];
        fence_();
        // (7,8) cell update: one b128 read gives (i,f,g,o) for unit q
        f32x4 g4 = *(const f32x4*)(&g_lds[grb]);
        c1 = fmaf(g4.y, c1, g4.x * g4.z);
        float th1 = fmaf(-2.0f, rcp_(1.0f + ex2_(2.0f * LOG2E * c1)), 1.0f);
        hy1 = g4.w * th1;
        h_lds[bl][q] = hy1;
        if (q < 4) {
            f32x4 g42 = *(const f32x4*)(&g_lds[grb + 64]);
            c2 = fmaf(g42.y, c2, g42.x * g42.z);
            float th2 = fmaf(-2.0f, rcp_(1.0f + ex2_(2.0f * LOG2E * c2)), 1.0f);
            hy2 = g42.w * th2;
            h_lds[bl][16 + q] = hy2;
        }
        fence_();
    };

    for (int t = 0; t < TSTEPS; t += 2) {
        body(t,     xB0, xB1);
        body(t + 1, xA0, xA1);
    }

    out[b * 20 + q] = hy1;
    if (q < 4) out[b * 20 + 16 + q] = hy2;
}

extern "C" void kernel_launch(void* const* d_in, const int* in_sizes, int n_in,
                              void* d_out, int out_size, void* d_ws, size_t ws_size,
                              hipStream_t stream) {
    const float* x    = (const float*)d_in[0];
    const float* W_ih = (const float*)d_in[1];
    const float* b_ih = (const float*)d_in[2];
    const float* W_hh = (const float*)d_in[3];
    const float* b_hh = (const float*)d_in[4];
    const float* hx0  = (const float*)d_in[5];
    const float* cx0  = (const float*)d_in[6];
    float* out = (float*)d_out;

    lstm_scan<<<dim3(256), dim3(256), 0, stream>>>(x, W_ih, b_ih, W_hh, b_hh,
                                                   hx0, cx0, out);
}